// Round 12
// baseline (75.258 us; speedup 1.0000x reference)
//
#include <hip/hip_runtime.h>
#include <hip/hip_bf16.h>

// ---------- types ----------
typedef float f32x4  __attribute__((ext_vector_type(4)));
typedef float f32x16 __attribute__((ext_vector_type(16)));
typedef __bf16 bfx8  __attribute__((ext_vector_type(8)));

#define NTOK 4096
#define NHEAD 8
#define DHEAD 64
#define NSPLIT 4
#define KCHUNK (NTOK / NSPLIT)

__device__ inline f32x4 mfma16(bfx8 a, bfx8 b, f32x4 c) {
    return __builtin_amdgcn_mfma_f32_16x16x32_bf16(a, b, c, 0, 0, 0);
}
__device__ inline f32x16 mfma32(bfx8 a, bfx8 b, f32x16 c) {
    return __builtin_amdgcn_mfma_f32_32x32x16_bf16(a, b, c, 0, 0, 0);
}

__device__ __forceinline__ void gld_lds16(const __bf16* g, __bf16* lds) {
    __builtin_amdgcn_global_load_lds(
        (const __attribute__((address_space(1))) void*)g,
        (__attribute__((address_space(3))) void*)lds, 16, 0, 0);
}

// ============================================================
// Kernel 0: cast/prep (unchanged from R11).
// ============================================================
__global__ __launch_bounds__(256) void cast_xw(
    const float* __restrict__ X, const float* __restrict__ Wqkv,
    const float* __restrict__ Wout,
    __bf16* __restrict__ Xb, __bf16* __restrict__ Wt, __bf16* __restrict__ Wot)
{
    __shared__ float Ws[64 * 68];
    const int bid = blockIdx.x;
    const int tid = threadIdx.x;

    if (bid < 256) {
        const float4* src = reinterpret_cast<const float4*>(X);
        int2* dst = reinterpret_cast<int2*>(Xb);
        int base = bid * 256 + tid;
#pragma unroll
        for (int i = 0; i < 4; ++i) {
            float4 v = src[base + i * 65536];
            union { __bf16 h[4]; int2 u; } o;
            o.h[0] = (__bf16)v.x; o.h[1] = (__bf16)v.y;
            o.h[2] = (__bf16)v.z; o.h[3] = (__bf16)v.w;
            dst[base + i * 65536] = o.u;
        }
    } else {
        const float* src; __bf16* dst;
        int kt, ft, srcPitch, dstPitch;
        if (bid < 352) {
            int b2 = bid - 256;
            kt = b2 / 24; ft = b2 % 24;
            src = Wqkv; srcPitch = 1536; dst = Wt; dstPitch = 256;
        } else {
            int b2 = bid - 352;
            kt = b2 >> 2; ft = b2 & 3;
            src = Wout; srcPitch = 256;  dst = Wot; dstPitch = 512;
        }
        int k0 = kt * 64, f0 = ft * 64;
#pragma unroll
        for (int rep = 0; rep < 4; ++rep) {
            int idx = rep * 256 + tid;
            int kr = idx >> 4;
            int c4 = idx & 15;
            float4 v = *reinterpret_cast<const float4*>(
                src + (size_t)(k0 + kr) * srcPitch + f0 + c4 * 4);
            *reinterpret_cast<float4*>(&Ws[kr * 68 + c4 * 4]) = v;
        }
        __syncthreads();
        int fr = tid & 63;
        int kg = tid >> 6;
        union { __bf16 h[8]; int4 u; } o0, o1;
#pragma unroll
        for (int j = 0; j < 8; ++j) o0.h[j] = (__bf16)Ws[(kg * 16 + j) * 68 + fr];
#pragma unroll
        for (int j = 0; j < 8; ++j) o1.h[j] = (__bf16)Ws[(kg * 16 + 8 + j) * 68 + fr];
        int4* d = reinterpret_cast<int4*>(dst + (size_t)(f0 + fr) * dstPitch + k0 + kg * 16);
        d[0] = o0.u; d[1] = o1.u;
    }
}

// ============================================================
// Kernel 1: QKV projection, pure bf16 (unchanged from R11).
// ============================================================
__global__ __launch_bounds__(256) void gemm_qkv_b(
    const __bf16* __restrict__ Xb, const __bf16* __restrict__ Wt,
    __bf16* __restrict__ Q, __bf16* __restrict__ Kb, __bf16* __restrict__ Vt)
{
    __shared__ __bf16 As[128 * 64];
    __shared__ __bf16 Bs[128 * 64];
    const int tid  = threadIdx.x;
    const int lane = tid & 63;
    const int wv   = tid >> 6;
    const int wr   = wv >> 1, wc = wv & 1;
    const int m0 = blockIdx.y * 128;
    const int n0 = blockIdx.x * 128;
    const int l15 = lane & 15, l4 = lane >> 4;

    f32x4 zero = {0.f, 0.f, 0.f, 0.f};
    f32x4 acc[4][4];
#pragma unroll
    for (int i = 0; i < 4; ++i)
#pragma unroll
        for (int j = 0; j < 4; ++j) acc[i][j] = zero;

    const int srow8 = lane >> 3;
    const int sslot = lane & 7;

    for (int k0 = 0; k0 < 256; k0 += 64) {
#pragma unroll
        for (int j = 0; j < 4; ++j) {
            int rbase = j * 32 + wv * 8;
            int row   = rbase + srow8;
            int slot  = sslot ^ (row & 7);
            gld_lds16(Xb + (size_t)(m0 + row) * 256 + k0 + slot * 8, &As[rbase * 64]);
            gld_lds16(Wt + (size_t)(n0 + row) * 256 + k0 + slot * 8, &Bs[rbase * 64]);
        }
        __syncthreads();

#pragma unroll
        for (int s = 0; s < 2; ++s) {
            bfx8 af[4], bf_[4];
#pragma unroll
            for (int m = 0; m < 4; ++m) {
                int row = wr * 64 + m * 16 + l15;
                af[m] = *reinterpret_cast<const bfx8*>(
                    reinterpret_cast<const char*>(As) + row * 128 +
                    (((s * 4 + l4) * 16) ^ ((row & 7) << 4)));
            }
#pragma unroll
            for (int n = 0; n < 4; ++n) {
                int row = wc * 64 + n * 16 + l15;
                bf_[n] = *reinterpret_cast<const bfx8*>(
                    reinterpret_cast<const char*>(Bs) + row * 128 +
                    (((s * 4 + l4) * 16) ^ ((row & 7) << 4)));
            }
#pragma unroll
            for (int m = 0; m < 4; ++m)
#pragma unroll
                for (int n = 0; n < 4; ++n)
                    acc[m][n] = mfma16(af[m], bf_[n], acc[m][n]);
        }
        __syncthreads();
    }

    const float QSCALE = 0.125f * 1.44269504088896f;
#pragma unroll
    for (int m = 0; m < 4; ++m)
#pragma unroll
        for (int n = 0; n < 4; ++n) {
            int rowb = m0 + wr * 64 + m * 16 + l4 * 4;
            int f    = n0 + wc * 64 + n * 16 + l15;
            if (f < 512) {
#pragma unroll
                for (int r = 0; r < 4; ++r)
                    Q[(size_t)(f >> 6) * (NTOK * DHEAD) + (size_t)(rowb + r) * DHEAD + (f & 63)] =
                        (__bf16)(acc[m][n][r] * QSCALE);
            } else if (f < 1024) {
                int g = f - 512;
#pragma unroll
                for (int r = 0; r < 4; ++r)
                    Kb[(size_t)(g >> 6) * (NTOK * DHEAD) + (size_t)(rowb + r) * DHEAD + (g & 63)] =
                        (__bf16)acc[m][n][r];
            } else {
                int g = f - 1024;
                union { __bf16 h[4]; int2 u; } o;
                o.h[0] = (__bf16)acc[m][n][0]; o.h[1] = (__bf16)acc[m][n][1];
                o.h[2] = (__bf16)acc[m][n][2]; o.h[3] = (__bf16)acc[m][n][3];
                *reinterpret_cast<int2*>(
                    Vt + (size_t)(g >> 6) * (DHEAD * NTOK) + (size_t)(g & 63) * NTOK + rowb) = o.u;
            }
        }
}

// ============================================================
// softmax+pack macro: 16 exp2 -> sum into l0 -> bf16 pack -> permlane
// ============================================================
#define SM_PACK(SA, F1, F2)                                                   \
    {                                                                         \
        float e0  = __builtin_amdgcn_exp2f(SA[0]);                            \
        float e1  = __builtin_amdgcn_exp2f(SA[1]);                            \
        float e2  = __builtin_amdgcn_exp2f(SA[2]);                            \
        float e3  = __builtin_amdgcn_exp2f(SA[3]);                            \
        float e4  = __builtin_amdgcn_exp2f(SA[4]);                            \
        float e5  = __builtin_amdgcn_exp2f(SA[5]);                            \
        float e6  = __builtin_amdgcn_exp2f(SA[6]);                            \
        float e7  = __builtin_amdgcn_exp2f(SA[7]);                            \
        float e8  = __builtin_amdgcn_exp2f(SA[8]);                            \
        float e9  = __builtin_amdgcn_exp2f(SA[9]);                            \
        float e10 = __builtin_amdgcn_exp2f(SA[10]);                           \
        float e11 = __builtin_amdgcn_exp2f(SA[11]);                           \
        float e12 = __builtin_amdgcn_exp2f(SA[12]);                           \
        float e13 = __builtin_amdgcn_exp2f(SA[13]);                           \
        float e14 = __builtin_amdgcn_exp2f(SA[14]);                           \
        float e15 = __builtin_amdgcn_exp2f(SA[15]);                           \
        l0 += (((e0 + e1) + (e2 + e3)) + ((e4 + e5) + (e6 + e7)))             \
            + (((e8 + e9) + (e10 + e11)) + ((e12 + e13) + (e14 + e15)));      \
        unsigned int b0, b1, b2, b3, b4, b5, b6, b7;                          \
        asm("v_cvt_pk_bf16_f32 %0, %1, %2" : "=v"(b0) : "v"(e0),  "v"(e1));   \
        asm("v_cvt_pk_bf16_f32 %0, %1, %2" : "=v"(b1) : "v"(e2),  "v"(e3));   \
        asm("v_cvt_pk_bf16_f32 %0, %1, %2" : "=v"(b2) : "v"(e4),  "v"(e5));   \
        asm("v_cvt_pk_bf16_f32 %0, %1, %2" : "=v"(b3) : "v"(e6),  "v"(e7));   \
        asm("v_cvt_pk_bf16_f32 %0, %1, %2" : "=v"(b4) : "v"(e8),  "v"(e9));   \
        asm("v_cvt_pk_bf16_f32 %0, %1, %2" : "=v"(b5) : "v"(e10), "v"(e11));  \
        asm("v_cvt_pk_bf16_f32 %0, %1, %2" : "=v"(b6) : "v"(e12), "v"(e13));  \
        asm("v_cvt_pk_bf16_f32 %0, %1, %2" : "=v"(b7) : "v"(e14), "v"(e15));  \
        asm("v_permlane32_swap_b32 %0, %1" : "+v"(b0), "+v"(b2));             \
        asm("v_permlane32_swap_b32 %0, %1" : "+v"(b1), "+v"(b3));             \
        asm("v_permlane32_swap_b32 %0, %1" : "+v"(b4), "+v"(b6));             \
        asm("v_permlane32_swap_b32 %0, %1" : "+v"(b5), "+v"(b7));             \
        F1.u[0] = b0; F1.u[1] = b1; F1.u[2] = b2; F1.u[3] = b3;               \
        F2.u[0] = b4; F2.u[1] = b5; F2.u[2] = b6; F2.u[3] = b7;               \
    }

#define PV_ACC(KB, F1, F2)                                                        \
    {                                                                             \
        int cb0 = ((KB) * 64 + hi * 16) ^ ksw;                                    \
        bfx8 vf00 = *reinterpret_cast<const bfx8*>(Vtc + l31 * 128 + cb0);        \
        o0 = mfma32(F1.v, vf00, o0);                                              \
        bfx8 vf01 = *reinterpret_cast<const bfx8*>(Vtc + (32 + l31) * 128 + cb0); \
        o1 = mfma32(F1.v, vf01, o1);                                              \
        int cb1 = ((KB) * 64 + 32 + hi * 16) ^ ksw;                               \
        bfx8 vf10 = *reinterpret_cast<const bfx8*>(Vtc + l31 * 128 + cb1);        \
        o0 = mfma32(F2.v, vf10, o0);                                              \
        bfx8 vf11 = *reinterpret_cast<const bfx8*>(Vtc + (32 + l31) * 128 + cb1); \
        o1 = mfma32(F2.v, vf11, o1);                                              \
    }

// ============================================================
// Kernel 2: flash attention, no-max softmax, cross-pipe interleaved:
// QK(kb0)+QK(kb1) MFMA chains first, then SM0 -> PV0 -> SM1 -> PV1 so
// SM trans ops overlap PV/QK MFMAs across the unrolled body.
// ============================================================
__global__ __launch_bounds__(512, 4) void attn_fwd(
    const __bf16* __restrict__ Q, const __bf16* __restrict__ Kb,
    const __bf16* __restrict__ Vt,
    __bf16* __restrict__ Opart, float* __restrict__ Lsum)
{
    const int tid  = threadIdx.x;
    const int lane = tid & 63;
    const int wv   = tid >> 6;          // 0..7
    const int bid = blockIdx.x;
    const int h  = bid & 7;
    const int t2 = bid >> 3;
    const int sp = t2 & (NSPLIT - 1);
    const int qb = t2 >> 2;             // 0..15
    const int l31 = lane & 31;
    const int hi  = lane >> 5;

    const __bf16* Qh = Q  + (size_t)h * NTOK * DHEAD;
    const __bf16* Kh = Kb + (size_t)h * NTOK * DHEAD;
    const __bf16* Vh = Vt + (size_t)h * DHEAD * NTOK;

    __shared__ __bf16 Ks[2][64 * 64];
    __shared__ __bf16 Vs[2][64 * 64];

    const int srow  = tid >> 3;
    const int scol8 = (tid & 7) ^ (srow & 7);

    const int qrow = qb * 256 + wv * 32 + l31;
    bfx8 qf[4];
#pragma unroll
    for (int s = 0; s < 4; ++s)
        qf[s] = *reinterpret_cast<const bfx8*>(
            Qh + (size_t)qrow * DHEAD + s * 16 + hi * 8);

    f32x16 o0, o1;
#pragma unroll
    for (int r = 0; r < 16; ++r) { o0[r] = 0.f; o1[r] = 0.f; }
    float l0 = 0.f;

    const int jbeg = sp * KCHUNK, jend = jbeg + KCHUNK;
    const int ksw = (l31 & 7) << 4;

    auto stage = [&](int bf, int j0) {
        gld_lds16(Kh + (size_t)(j0 + srow) * DHEAD + scol8 * 8, &Ks[bf][wv * 8 * 64]);
        gld_lds16(Vh + (size_t)srow * NTOK + j0 + scol8 * 8,    &Vs[bf][wv * 8 * 64]);
    };

    stage(0, jbeg);
    __syncthreads();

    int buf = 0;
    for (int j0 = jbeg; j0 < jend; j0 += 64) {
        if (j0 + 64 < jend) stage(buf ^ 1, j0 + 64);

        const char* Kt  = reinterpret_cast<const char*>(&Ks[buf][0]);
        const char* Vtc = reinterpret_cast<const char*>(&Vs[buf][0]);

        // ---- QK^T both halves: two independent 4-MFMA chains ----
        const char* Kr0 = Kt + l31 * 128;
        const char* Kr1 = Kt + (32 + l31) * 128;
        f32x16 sa0, sa1;
#pragma unroll
        for (int r = 0; r < 16; ++r) { sa0[r] = 0.f; sa1[r] = 0.f; }
        __builtin_amdgcn_s_setprio(1);
#pragma unroll
        for (int s = 0; s < 4; ++s) {
            bfx8 kf0 = *reinterpret_cast<const bfx8*>(Kr0 + (((s * 2 + hi) * 16) ^ ksw));
            sa0 = mfma32(kf0, qf[s], sa0);
        }
#pragma unroll
        for (int s = 0; s < 4; ++s) {
            bfx8 kf1 = *reinterpret_cast<const bfx8*>(Kr1 + (((s * 2 + hi) * 16) ^ ksw));
            sa1 = mfma32(kf1, qf[s], sa1);
        }
        __builtin_amdgcn_s_setprio(0);

        // ---- SM0 / PV0 / SM1 / PV1 (trans overlaps MFMA) ----
        union { unsigned int u[4]; bfx8 v; } f10, f20, f11, f21;
        SM_PACK(sa0, f10, f20);
        __builtin_amdgcn_s_setprio(1);
        PV_ACC(0, f10, f20);
        __builtin_amdgcn_s_setprio(0);
        SM_PACK(sa1, f11, f21);
        __builtin_amdgcn_s_setprio(1);
        PV_ACC(1, f11, f21);
        __builtin_amdgcn_s_setprio(0);

        __syncthreads();
        buf ^= 1;
    }

    float l_l = l0 + __shfl_xor(l0, 32, 64);

    // ---- store unnormalized partial O (bf16) + per-row l ----
#pragma unroll
    for (int r = 0; r < 16; ++r) {
        int q = (r & 3) + 8 * (r >> 2) + 4 * hi;
        size_t row = (size_t)(qb * 256 + wv * 32 + q);
        __bf16* dst = Opart + ((size_t)sp * NTOK + row) * 512 + h * 64 + l31;
        dst[0]  = (__bf16)o0[r];
        dst[32] = (__bf16)o1[r];
    }
    if (hi == 0) {
        Lsum[((size_t)sp * NHEAD + h) * NTOK + qrow] = l_l;
    }
}

// ============================================================
// Kernel 3: output projection with fused split-combine.
// A-tile = normalize(sum of NSPLIT bf16 partials) built in registers
// (head h = k0>>6 is constant per k-step). B = Wot via gld_lds.
// ============================================================
__global__ __launch_bounds__(256) void gemm_out_f(
    const __bf16* __restrict__ Opart, const float* __restrict__ Lsum,
    const __bf16* __restrict__ Wot, const float* __restrict__ bias,
    float* __restrict__ out)
{
    __shared__ __bf16 As[64 * 64];
    __shared__ __bf16 Bs[64 * 64];
    const int tid  = threadIdx.x;
    const int lane = tid & 63;
    const int wv   = tid >> 6;
    const int wr   = wv >> 1, wc = wv & 1;
    const int m0 = blockIdx.y * 64;
    const int n0 = blockIdx.x * 64;
    const int l15 = lane & 15, l4 = lane >> 4;

    f32x4 zero = {0.f, 0.f, 0.f, 0.f};
    f32x4 acc[2][2];
#pragma unroll
    for (int i = 0; i < 2; ++i)
#pragma unroll
        for (int j = 0; j < 2; ++j) acc[i][j] = zero;

    const int srow8 = lane >> 3;
    const int sslot = lane & 7;
    const int arow  = tid >> 2;       // 0..63
    const int aseg  = tid & 3;        // 16-col segment

    for (int k0 = 0; k0 < 512; k0 += 64) {
        const int h = k0 >> 6;
        // ---- stage B (Wot rows = out-cols) via gld_lds ----
#pragma unroll
        for (int j = 0; j < 2; ++j) {
            int rbase = j * 32 + wv * 8;
            int row   = rbase + srow8;
            int slot  = sslot ^ (row & 7);
            gld_lds16(Wot + (size_t)(n0 + row) * 512 + k0 + slot * 8, &Bs[rbase * 64]);
        }
        // ---- stage A: combine NSPLIT partials, normalize, bf16 ----
        {
            int grow = m0 + arow;
            float d = Lsum[(size_t)(0 * NHEAD + h) * NTOK + grow]
                    + Lsum[(size_t)(1 * NHEAD + h) * NTOK + grow]
                    + Lsum[(size_t)(2 * NHEAD + h) * NTOK + grow]
                    + Lsum[(size_t)(3 * NHEAD + h) * NTOK + grow];
            float inv = 1.f / d;
            float fa[16];
#pragma unroll
            for (int j = 0; j < 16; ++j) fa[j] = 0.f;
#pragma unroll
            for (int s = 0; s < NSPLIT; ++s) {
                union { int4 u; __bf16 hh[8]; } v0, v1;
                const __bf16* src = Opart + ((size_t)s * NTOK + grow) * 512 + k0 + aseg * 16;
                v0.u = *reinterpret_cast<const int4*>(src);
                v1.u = *reinterpret_cast<const int4*>(src + 8);
#pragma unroll
                for (int j = 0; j < 8; ++j) fa[j]     += (float)v0.hh[j];
#pragma unroll
                for (int j = 0; j < 8; ++j) fa[8 + j] += (float)v1.hh[j];
            }
            union { __bf16 hh[8]; int4 u; } w0, w1;
#pragma unroll
            for (int j = 0; j < 8; ++j) w0.hh[j] = (__bf16)(fa[j] * inv);
#pragma unroll
            for (int j = 0; j < 8; ++j) w1.hh[j] = (__bf16)(fa[8 + j] * inv);
            char* ab = reinterpret_cast<char*>(As) + arow * 128;
            int slot0 = (aseg * 2)     ^ (arow & 7);
            int slot1 = (aseg * 2 + 1) ^ (arow & 7);
            *reinterpret_cast<int4*>(ab + slot0 * 16) = w0.u;
            *reinterpret_cast<int4*>(ab + slot1 * 16) = w1.u;
        }
        __syncthreads();

#pragma unroll
        for (int s = 0; s < 2; ++s) {
            bfx8 af[2], bf_[2];
#pragma unroll
            for (int m = 0; m < 2; ++m) {
                int row = wr * 32 + m * 16 + l15;
                af[m] = *reinterpret_cast<const bfx8*>(
                    reinterpret_cast<const char*>(As) + row * 128 +
                    (((s * 4 + l4) * 16) ^ ((row & 7) << 4)));
            }
#pragma unroll
            for (int n = 0; n < 2; ++n) {
                int row = wc * 32 + n * 16 + l15;
                bf_[n] = *reinterpret_cast<const bfx8*>(
                    reinterpret_cast<const char*>(Bs) + row * 128 +
                    (((s * 4 + l4) * 16) ^ ((row & 7) << 4)));
            }
#pragma unroll
            for (int m = 0; m < 2; ++m)
#pragma unroll
                for (int n = 0; n < 2; ++n)
                    acc[m][n] = mfma16(af[m], bf_[n], acc[m][n]);
        }
        __syncthreads();
    }

#pragma unroll
    for (int m = 0; m < 2; ++m)
#pragma unroll
        for (int n = 0; n < 2; ++n) {
            int col = n0 + wc * 32 + n * 16 + l15;
            float b = bias[col];
#pragma unroll
            for (int r = 0; r < 4; ++r) {
                int row = m0 + wr * 32 + m * 16 + l4 * 4 + r;
                out[(size_t)row * 256 + col] = acc[m][n][r] + b;
            }
        }
}

// ============================================================
extern "C" void kernel_launch(void* const* d_in, const int* in_sizes, int n_in,
                              void* d_out, int out_size, void* d_ws, size_t ws_size,
                              hipStream_t stream) {
    const float* x     = (const float*)d_in[0];
    const float* w_qkv = (const float*)d_in[1];
    const float* w_out = (const float*)d_in[2];
    const float* b_out = (const float*)d_in[3];
    float* out = (float*)d_out;

    // ws: Q,K,Vt 12MB | Opart bf16 [4][4096][512] 16MB | Lsum [4][8][4096] 0.5MB
    //     Xb 2MB | Wt 0.75MB | Wot 0.25MB
    __bf16* Q  = (__bf16*)d_ws;
    __bf16* K  = Q  + (size_t)NHEAD * NTOK * DHEAD;
    __bf16* Vt = K  + (size_t)NHEAD * NTOK * DHEAD;
    __bf16* Opart = Vt + (size_t)NHEAD * NTOK * DHEAD;
    float* Lsum = (float*)(Opart + (size_t)NSPLIT * NTOK * 512);
    __bf16* Xb = (__bf16*)(Lsum + (size_t)NSPLIT * NHEAD * NTOK);
    __bf16* Wt = Xb + (size_t)NTOK * 256;
    __bf16* Wot = Wt + (size_t)1536 * 256;

    cast_xw   <<<dim3(384), 256, 0, stream>>>(x, w_qkv, w_out, Xb, Wt, Wot);
    gemm_qkv_b<<<dim3(12, 32), 256, 0, stream>>>(Xb, Wt, Q, K, Vt);
    attn_fwd  <<<dim3((NTOK / 256) * NSPLIT * NHEAD), 512, 0, stream>>>(Q, K, Vt, Opart, Lsum);
    gemm_out_f<<<dim3(256 / 64, NTOK / 64), 256, 0, stream>>>(Opart, Lsum, Wot, b_out, out);
}

// Round 13
// 71.846 us; speedup vs baseline: 1.0475x; 1.0475x over previous
//
#include <hip/hip_runtime.h>
#include <hip/hip_bf16.h>

// ---------- types ----------
typedef float f32x4  __attribute__((ext_vector_type(4)));
typedef float f32x16 __attribute__((ext_vector_type(16)));
typedef __bf16 bfx8  __attribute__((ext_vector_type(8)));

#define NTOK 4096
#define NHEAD 8
#define DHEAD 64
#define NSPLIT 4
#define KCHUNK (NTOK / NSPLIT)

__device__ inline f32x4 mfma16(bfx8 a, bfx8 b, f32x4 c) {
    return __builtin_amdgcn_mfma_f32_16x16x32_bf16(a, b, c, 0, 0, 0);
}
__device__ inline f32x16 mfma32(bfx8 a, bfx8 b, f32x16 c) {
    return __builtin_amdgcn_mfma_f32_32x32x16_bf16(a, b, c, 0, 0, 0);
}

__device__ __forceinline__ void gld_lds16(const __bf16* g, __bf16* lds) {
    __builtin_amdgcn_global_load_lds(
        (const __attribute__((address_space(1))) void*)g,
        (__attribute__((address_space(3))) void*)lds, 16, 0, 0);
}

// ============================================================
// Kernel 0: cast/prep.
// ============================================================
__global__ __launch_bounds__(256) void cast_xw(
    const float* __restrict__ X, const float* __restrict__ Wqkv,
    const float* __restrict__ Wout,
    __bf16* __restrict__ Xb, __bf16* __restrict__ Wt, __bf16* __restrict__ Wot)
{
    __shared__ float Ws[64 * 68];
    const int bid = blockIdx.x;
    const int tid = threadIdx.x;

    if (bid < 256) {
        const float4* src = reinterpret_cast<const float4*>(X);
        int2* dst = reinterpret_cast<int2*>(Xb);
        int base = bid * 256 + tid;
#pragma unroll
        for (int i = 0; i < 4; ++i) {
            float4 v = src[base + i * 65536];
            union { __bf16 h[4]; int2 u; } o;
            o.h[0] = (__bf16)v.x; o.h[1] = (__bf16)v.y;
            o.h[2] = (__bf16)v.z; o.h[3] = (__bf16)v.w;
            dst[base + i * 65536] = o.u;
        }
    } else {
        const float* src; __bf16* dst;
        int kt, ft, srcPitch, dstPitch;
        if (bid < 352) {
            int b2 = bid - 256;
            kt = b2 / 24; ft = b2 % 24;
            src = Wqkv; srcPitch = 1536; dst = Wt; dstPitch = 256;
        } else {
            int b2 = bid - 352;
            kt = b2 >> 2; ft = b2 & 3;
            src = Wout; srcPitch = 256;  dst = Wot; dstPitch = 512;
        }
        int k0 = kt * 64, f0 = ft * 64;
#pragma unroll
        for (int rep = 0; rep < 4; ++rep) {
            int idx = rep * 256 + tid;
            int kr = idx >> 4;
            int c4 = idx & 15;
            float4 v = *reinterpret_cast<const float4*>(
                src + (size_t)(k0 + kr) * srcPitch + f0 + c4 * 4);
            *reinterpret_cast<float4*>(&Ws[kr * 68 + c4 * 4]) = v;
        }
        __syncthreads();
        int fr = tid & 63;
        int kg = tid >> 6;
        union { __bf16 h[8]; int4 u; } o0, o1;
#pragma unroll
        for (int j = 0; j < 8; ++j) o0.h[j] = (__bf16)Ws[(kg * 16 + j) * 68 + fr];
#pragma unroll
        for (int j = 0; j < 8; ++j) o1.h[j] = (__bf16)Ws[(kg * 16 + 8 + j) * 68 + fr];
        int4* d = reinterpret_cast<int4*>(dst + (size_t)(f0 + fr) * dstPitch + k0 + kg * 16);
        d[0] = o0.u; d[1] = o1.u;
    }
}

// ============================================================
// Kernel 1: QKV projection, pure bf16.
// ============================================================
__global__ __launch_bounds__(256) void gemm_qkv_b(
    const __bf16* __restrict__ Xb, const __bf16* __restrict__ Wt,
    __bf16* __restrict__ Q, __bf16* __restrict__ Kb, __bf16* __restrict__ Vt)
{
    __shared__ __bf16 As[128 * 64];
    __shared__ __bf16 Bs[128 * 64];
    const int tid  = threadIdx.x;
    const int lane = tid & 63;
    const int wv   = tid >> 6;
    const int wr   = wv >> 1, wc = wv & 1;
    const int m0 = blockIdx.y * 128;
    const int n0 = blockIdx.x * 128;
    const int l15 = lane & 15, l4 = lane >> 4;

    f32x4 zero = {0.f, 0.f, 0.f, 0.f};
    f32x4 acc[4][4];
#pragma unroll
    for (int i = 0; i < 4; ++i)
#pragma unroll
        for (int j = 0; j < 4; ++j) acc[i][j] = zero;

    const int srow8 = lane >> 3;
    const int sslot = lane & 7;

    for (int k0 = 0; k0 < 256; k0 += 64) {
#pragma unroll
        for (int j = 0; j < 4; ++j) {
            int rbase = j * 32 + wv * 8;
            int row   = rbase + srow8;
            int slot  = sslot ^ (row & 7);
            gld_lds16(Xb + (size_t)(m0 + row) * 256 + k0 + slot * 8, &As[rbase * 64]);
            gld_lds16(Wt + (size_t)(n0 + row) * 256 + k0 + slot * 8, &Bs[rbase * 64]);
        }
        __syncthreads();

#pragma unroll
        for (int s = 0; s < 2; ++s) {
            bfx8 af[4], bf_[4];
#pragma unroll
            for (int m = 0; m < 4; ++m) {
                int row = wr * 64 + m * 16 + l15;
                af[m] = *reinterpret_cast<const bfx8*>(
                    reinterpret_cast<const char*>(As) + row * 128 +
                    (((s * 4 + l4) * 16) ^ ((row & 7) << 4)));
            }
#pragma unroll
            for (int n = 0; n < 4; ++n) {
                int row = wc * 64 + n * 16 + l15;
                bf_[n] = *reinterpret_cast<const bfx8*>(
                    reinterpret_cast<const char*>(Bs) + row * 128 +
                    (((s * 4 + l4) * 16) ^ ((row & 7) << 4)));
            }
#pragma unroll
            for (int m = 0; m < 4; ++m)
#pragma unroll
                for (int n = 0; n < 4; ++n)
                    acc[m][n] = mfma16(af[m], bf_[n], acc[m][n]);
        }
        __syncthreads();
    }

    const float QSCALE = 0.125f * 1.44269504088896f;
#pragma unroll
    for (int m = 0; m < 4; ++m)
#pragma unroll
        for (int n = 0; n < 4; ++n) {
            int rowb = m0 + wr * 64 + m * 16 + l4 * 4;
            int f    = n0 + wc * 64 + n * 16 + l15;
            if (f < 512) {
#pragma unroll
                for (int r = 0; r < 4; ++r)
                    Q[(size_t)(f >> 6) * (NTOK * DHEAD) + (size_t)(rowb + r) * DHEAD + (f & 63)] =
                        (__bf16)(acc[m][n][r] * QSCALE);
            } else if (f < 1024) {
                int g = f - 512;
#pragma unroll
                for (int r = 0; r < 4; ++r)
                    Kb[(size_t)(g >> 6) * (NTOK * DHEAD) + (size_t)(rowb + r) * DHEAD + (g & 63)] =
                        (__bf16)acc[m][n][r];
            } else {
                int g = f - 1024;
                union { __bf16 h[4]; int2 u; } o;
                o.h[0] = (__bf16)acc[m][n][0]; o.h[1] = (__bf16)acc[m][n][1];
                o.h[2] = (__bf16)acc[m][n][2]; o.h[3] = (__bf16)acc[m][n][3];
                *reinterpret_cast<int2*>(
                    Vt + (size_t)(g >> 6) * (DHEAD * NTOK) + (size_t)(g & 63) * NTOK + rowb) = o.u;
            }
        }
}

// ============================================================
// Kernel 2: flash attention (R11 structure, no-max softmax).
// Epilogue: pack (o0[r], o1[r]) -> one u32 word, Opart layout
// [sp][row][h][32] words (lo16 = col l31, hi16 = col l31+32).
// ============================================================
__global__ __launch_bounds__(512, 4) void attn_fwd(
    const __bf16* __restrict__ Q, const __bf16* __restrict__ Kb,
    const __bf16* __restrict__ Vt,
    unsigned int* __restrict__ Opu, float* __restrict__ Lsum)
{
    const int tid  = threadIdx.x;
    const int lane = tid & 63;
    const int wv   = tid >> 6;          // 0..7
    const int bid = blockIdx.x;
    const int h  = bid & 7;
    const int t2 = bid >> 3;
    const int sp = t2 & (NSPLIT - 1);
    const int qb = t2 >> 2;             // 0..15
    const int l31 = lane & 31;
    const int hi  = lane >> 5;

    const __bf16* Qh = Q  + (size_t)h * NTOK * DHEAD;
    const __bf16* Kh = Kb + (size_t)h * NTOK * DHEAD;
    const __bf16* Vh = Vt + (size_t)h * DHEAD * NTOK;

    __shared__ __bf16 Ks[2][64 * 64];
    __shared__ __bf16 Vs[2][64 * 64];

    const int srow  = tid >> 3;
    const int scol8 = (tid & 7) ^ (srow & 7);

    const int qrow = qb * 256 + wv * 32 + l31;
    bfx8 qf[4];
#pragma unroll
    for (int s = 0; s < 4; ++s)
        qf[s] = *reinterpret_cast<const bfx8*>(
            Qh + (size_t)qrow * DHEAD + s * 16 + hi * 8);

    f32x16 o0, o1;
#pragma unroll
    for (int r = 0; r < 16; ++r) { o0[r] = 0.f; o1[r] = 0.f; }
    float l_l = 0.f;

    const int jbeg = sp * KCHUNK, jend = jbeg + KCHUNK;
    const int ksw = (l31 & 7) << 4;

    auto stage = [&](int bf, int j0) {
        gld_lds16(Kh + (size_t)(j0 + srow) * DHEAD + scol8 * 8, &Ks[bf][wv * 8 * 64]);
        gld_lds16(Vh + (size_t)srow * NTOK + j0 + scol8 * 8,    &Vs[bf][wv * 8 * 64]);
    };

    stage(0, jbeg);
    __syncthreads();

    int buf = 0;
    for (int j0 = jbeg; j0 < jend; j0 += 64) {
        if (j0 + 64 < jend) stage(buf ^ 1, j0 + 64);

        const char* Kt  = reinterpret_cast<const char*>(&Ks[buf][0]);
        const char* Vtc = reinterpret_cast<const char*>(&Vs[buf][0]);

#pragma unroll
        for (int kb = 0; kb < 2; ++kb) {
            // ---- S' = K Q^T : lane holds S[key(r,hi)][q=l31] ----
            const char* Kr = Kt + (kb * 32 + l31) * 128;
            f32x16 sa;
#pragma unroll
            for (int r = 0; r < 16; ++r) sa[r] = 0.f;
            __builtin_amdgcn_s_setprio(1);
#pragma unroll
            for (int s = 0; s < 4; ++s) {
                bfx8 kf = *reinterpret_cast<const bfx8*>(Kr + (((s * 2 + hi) * 16) ^ ksw));
                sa = mfma32(kf, qf[s], sa);
            }
            __builtin_amdgcn_s_setprio(0);

            // ---- P = exp2(S) directly (no max subtraction needed) ----
            float p0  = __builtin_amdgcn_exp2f(sa[0]);
            float p1  = __builtin_amdgcn_exp2f(sa[1]);
            float p2  = __builtin_amdgcn_exp2f(sa[2]);
            float p3  = __builtin_amdgcn_exp2f(sa[3]);
            float p4  = __builtin_amdgcn_exp2f(sa[4]);
            float p5  = __builtin_amdgcn_exp2f(sa[5]);
            float p6  = __builtin_amdgcn_exp2f(sa[6]);
            float p7  = __builtin_amdgcn_exp2f(sa[7]);
            float p8  = __builtin_amdgcn_exp2f(sa[8]);
            float p9  = __builtin_amdgcn_exp2f(sa[9]);
            float p10 = __builtin_amdgcn_exp2f(sa[10]);
            float p11 = __builtin_amdgcn_exp2f(sa[11]);
            float p12 = __builtin_amdgcn_exp2f(sa[12]);
            float p13 = __builtin_amdgcn_exp2f(sa[13]);
            float p14 = __builtin_amdgcn_exp2f(sa[14]);
            float p15 = __builtin_amdgcn_exp2f(sa[15]);
            float ps = ((p0 + p1) + (p2 + p3)) + ((p4 + p5) + (p6 + p7))
                     + ((p8 + p9) + (p10 + p11)) + ((p12 + p13) + (p14 + p15));
            ps += __shfl_xor(ps, 32, 64);
            l_l += ps;

            unsigned int a0, a1, a2, a3, a4, a5, a6, a7;
            asm("v_cvt_pk_bf16_f32 %0, %1, %2" : "=v"(a0) : "v"(p0),  "v"(p1));
            asm("v_cvt_pk_bf16_f32 %0, %1, %2" : "=v"(a1) : "v"(p2),  "v"(p3));
            asm("v_cvt_pk_bf16_f32 %0, %1, %2" : "=v"(a2) : "v"(p4),  "v"(p5));
            asm("v_cvt_pk_bf16_f32 %0, %1, %2" : "=v"(a3) : "v"(p6),  "v"(p7));
            asm("v_cvt_pk_bf16_f32 %0, %1, %2" : "=v"(a4) : "v"(p8),  "v"(p9));
            asm("v_cvt_pk_bf16_f32 %0, %1, %2" : "=v"(a5) : "v"(p10), "v"(p11));
            asm("v_cvt_pk_bf16_f32 %0, %1, %2" : "=v"(a6) : "v"(p12), "v"(p13));
            asm("v_cvt_pk_bf16_f32 %0, %1, %2" : "=v"(a7) : "v"(p14), "v"(p15));
            asm("v_permlane32_swap_b32 %0, %1" : "+v"(a0), "+v"(a2));
            asm("v_permlane32_swap_b32 %0, %1" : "+v"(a1), "+v"(a3));
            asm("v_permlane32_swap_b32 %0, %1" : "+v"(a4), "+v"(a6));
            asm("v_permlane32_swap_b32 %0, %1" : "+v"(a5), "+v"(a7));
            union { unsigned int u[4]; bfx8 v; } f1, f2;
            f1.u[0] = a0; f1.u[1] = a1; f1.u[2] = a2; f1.u[3] = a3;
            f2.u[0] = a4; f2.u[1] = a5; f2.u[2] = a6; f2.u[3] = a7;

            __builtin_amdgcn_s_setprio(1);
            {
                int cb0 = (kb * 64 + hi * 16) ^ ksw;
                bfx8 vf00 = *reinterpret_cast<const bfx8*>(Vtc + l31 * 128 + cb0);
                o0 = mfma32(f1.v, vf00, o0);
                bfx8 vf01 = *reinterpret_cast<const bfx8*>(Vtc + (32 + l31) * 128 + cb0);
                o1 = mfma32(f1.v, vf01, o1);
                int cb1 = (kb * 64 + 32 + hi * 16) ^ ksw;
                bfx8 vf10 = *reinterpret_cast<const bfx8*>(Vtc + l31 * 128 + cb1);
                o0 = mfma32(f2.v, vf10, o0);
                bfx8 vf11 = *reinterpret_cast<const bfx8*>(Vtc + (32 + l31) * 128 + cb1);
                o1 = mfma32(f2.v, vf11, o1);
            }
            __builtin_amdgcn_s_setprio(0);
        }

        __syncthreads();
        buf ^= 1;
    }

    // ---- store packed partial O (u32 = 2x bf16) + per-row l ----
#pragma unroll
    for (int r = 0; r < 16; ++r) {
        int q = (r & 3) + 8 * (r >> 2) + 4 * hi;
        size_t row = (size_t)(qb * 256 + wv * 32 + q);
        unsigned int w;
        asm("v_cvt_pk_bf16_f32 %0, %1, %2" : "=v"(w) : "v"(o0[r]), "v"(o1[r]));
        Opu[(((size_t)sp * NTOK + row) * NHEAD + h) * 32 + l31] = w;
    }
    if (hi == 0) {
        Lsum[((size_t)sp * NHEAD + h) * NTOK + qrow] = l_l;
    }
}

// ============================================================
// Kernel 2b: combine NSPLIT packed partials -> O bf16 [4096][512]
// ============================================================
__global__ __launch_bounds__(256) void attn_combine(
    const unsigned int* __restrict__ Opu, const float* __restrict__ Lsum,
    __bf16* __restrict__ O)
{
    int idx = blockIdx.x * 256 + threadIdx.x;      // 4096 * 128
    int row = idx >> 7;
    int c4  = (idx & 127) * 4;
    int h   = c4 >> 6;
    int cl  = c4 & 63;
    int hiSel = cl >> 5;              // 0: lo16 (cols 0..31), 1: hi16
    int base_cl = cl & 31;

    float denom = 0.f;
    float4 acc = make_float4(0.f, 0.f, 0.f, 0.f);
#pragma unroll
    for (int s = 0; s < NSPLIT; ++s) {
        denom += Lsum[((size_t)s * NHEAD + h) * NTOK + row];
        int4 w = *reinterpret_cast<const int4*>(
            Opu + (((size_t)s * NTOK + row) * NHEAD + h) * 32 + base_cl);
        unsigned int w0 = (unsigned int)w.x, w1 = (unsigned int)w.y;
        unsigned int w2 = (unsigned int)w.z, w3 = (unsigned int)w.w;
        if (hiSel) { w0 >>= 16; w1 >>= 16; w2 >>= 16; w3 >>= 16; }
        union { unsigned int u; float f; } c0, c1, c2, c3;
        c0.u = w0 << 16; c1.u = w1 << 16; c2.u = w2 << 16; c3.u = w3 << 16;
        acc.x += c0.f; acc.y += c1.f; acc.z += c2.f; acc.w += c3.f;
    }
    float inv = 1.f / denom;
    __bf16* op = O + (size_t)row * 512 + c4;
    op[0] = (__bf16)(acc.x * inv); op[1] = (__bf16)(acc.y * inv);
    op[2] = (__bf16)(acc.z * inv); op[3] = (__bf16)(acc.w * inv);
}

// ============================================================
// Kernel 3: output projection, pure bf16 staging (R11 version).
// ============================================================
__global__ __launch_bounds__(256) void gemm_out_b(
    const __bf16* __restrict__ O, const __bf16* __restrict__ Wot,
    const float* __restrict__ bias, float* __restrict__ out)
{
    __shared__ __bf16 As[64 * 64];
    __shared__ __bf16 Bs[64 * 64];
    const int tid  = threadIdx.x;
    const int lane = tid & 63;
    const int wv   = tid >> 6;
    const int wr   = wv >> 1, wc = wv & 1;
    const int m0 = blockIdx.y * 64;
    const int n0 = blockIdx.x * 64;
    const int l15 = lane & 15, l4 = lane >> 4;

    f32x4 zero = {0.f, 0.f, 0.f, 0.f};
    f32x4 acc[2][2];
#pragma unroll
    for (int i = 0; i < 2; ++i)
#pragma unroll
        for (int j = 0; j < 2; ++j) acc[i][j] = zero;

    const int srow8 = lane >> 3;
    const int sslot = lane & 7;

    for (int k0 = 0; k0 < 512; k0 += 64) {
#pragma unroll
        for (int j = 0; j < 2; ++j) {
            int rbase = j * 32 + wv * 8;
            int row   = rbase + srow8;
            int slot  = sslot ^ (row & 7);
            gld_lds16(O   + (size_t)(m0 + row) * 512 + k0 + slot * 8, &As[rbase * 64]);
            gld_lds16(Wot + (size_t)(n0 + row) * 512 + k0 + slot * 8, &Bs[rbase * 64]);
        }
        __syncthreads();

#pragma unroll
        for (int s = 0; s < 2; ++s) {
            bfx8 af[2], bf_[2];
#pragma unroll
            for (int m = 0; m < 2; ++m) {
                int row = wr * 32 + m * 16 + l15;
                af[m] = *reinterpret_cast<const bfx8*>(
                    reinterpret_cast<const char*>(As) + row * 128 +
                    (((s * 4 + l4) * 16) ^ ((row & 7) << 4)));
            }
#pragma unroll
            for (int n = 0; n < 2; ++n) {
                int row = wc * 32 + n * 16 + l15;
                bf_[n] = *reinterpret_cast<const bfx8*>(
                    reinterpret_cast<const char*>(Bs) + row * 128 +
                    (((s * 4 + l4) * 16) ^ ((row & 7) << 4)));
            }
#pragma unroll
            for (int m = 0; m < 2; ++m)
#pragma unroll
                for (int n = 0; n < 2; ++n)
                    acc[m][n] = mfma16(af[m], bf_[n], acc[m][n]);
        }
        __syncthreads();
    }

#pragma unroll
    for (int m = 0; m < 2; ++m)
#pragma unroll
        for (int n = 0; n < 2; ++n) {
            int col = n0 + wc * 32 + n * 16 + l15;
            float b = bias[col];
#pragma unroll
            for (int r = 0; r < 4; ++r) {
                int row = m0 + wr * 32 + m * 16 + l4 * 4 + r;
                out[(size_t)row * 256 + col] = acc[m][n][r] + b;
            }
        }
}

// ============================================================
extern "C" void kernel_launch(void* const* d_in, const int* in_sizes, int n_in,
                              void* d_out, int out_size, void* d_ws, size_t ws_size,
                              hipStream_t stream) {
    const float* x     = (const float*)d_in[0];
    const float* w_qkv = (const float*)d_in[1];
    const float* w_out = (const float*)d_in[2];
    const float* b_out = (const float*)d_in[3];
    float* out = (float*)d_out;

    // ws: Q,K,Vt 12MB | O 4MB | Opu u32 [4][4096][8][32] 16MB |
    //     Lsum [4][8][4096] 0.5MB | Xb 2MB | Wt 0.75MB | Wot 0.25MB
    __bf16* Q  = (__bf16*)d_ws;
    __bf16* K  = Q  + (size_t)NHEAD * NTOK * DHEAD;
    __bf16* Vt = K  + (size_t)NHEAD * NTOK * DHEAD;
    __bf16* O  = Vt + (size_t)NHEAD * NTOK * DHEAD;
    unsigned int* Opu = (unsigned int*)(O + (size_t)NTOK * 512);
    float* Lsum = (float*)(Opu + (size_t)NSPLIT * NTOK * NHEAD * 32);
    __bf16* Xb = (__bf16*)(Lsum + (size_t)NSPLIT * NHEAD * NTOK);
    __bf16* Wt = Xb + (size_t)NTOK * 256;
    __bf16* Wot = Wt + (size_t)1536 * 256;

    cast_xw     <<<dim3(384), 256, 0, stream>>>(x, w_qkv, w_out, Xb, Wt, Wot);
    gemm_qkv_b  <<<dim3(12, 32), 256, 0, stream>>>(Xb, Wt, Q, K, Vt);
    attn_fwd    <<<dim3((NTOK / 256) * NSPLIT * NHEAD), 512, 0, stream>>>(Q, K, Vt, Opu, Lsum);
    attn_combine<<<dim3(NTOK * 128 / 256), 256, 0, stream>>>(Opu, Lsum, O);
    gemm_out_b  <<<dim3(256 / 64, NTOK / 64), 256, 0, stream>>>(O, Wot, b_out, out);
}

// Round 14
// 69.919 us; speedup vs baseline: 1.0764x; 1.0276x over previous
//
#include <hip/hip_runtime.h>
#include <hip/hip_bf16.h>

// ---------- types ----------
typedef float f32x4  __attribute__((ext_vector_type(4)));
typedef float f32x16 __attribute__((ext_vector_type(16)));
typedef __bf16 bfx8  __attribute__((ext_vector_type(8)));

#define NTOK 4096
#define NHEAD 8
#define DHEAD 64
#define NSPLIT 4
#define KCHUNK (NTOK / NSPLIT)

__device__ inline f32x4 mfma16(bfx8 a, bfx8 b, f32x4 c) {
    return __builtin_amdgcn_mfma_f32_16x16x32_bf16(a, b, c, 0, 0, 0);
}
__device__ inline f32x16 mfma32(bfx8 a, bfx8 b, f32x16 c) {
    return __builtin_amdgcn_mfma_f32_32x32x16_bf16(a, b, c, 0, 0, 0);
}

__device__ __forceinline__ void gld_lds16(const __bf16* g, __bf16* lds) {
    __builtin_amdgcn_global_load_lds(
        (const __attribute__((address_space(1))) void*)g,
        (__attribute__((address_space(3))) void*)lds, 16, 0, 0);
}

// ============================================================
// Kernel 0: cast/prep (unchanged from R13).
// ============================================================
__global__ __launch_bounds__(256) void cast_xw(
    const float* __restrict__ X, const float* __restrict__ Wqkv,
    const float* __restrict__ Wout,
    __bf16* __restrict__ Xb, __bf16* __restrict__ Wt, __bf16* __restrict__ Wot)
{
    __shared__ float Ws[64 * 68];
    const int bid = blockIdx.x;
    const int tid = threadIdx.x;

    if (bid < 256) {
        const float4* src = reinterpret_cast<const float4*>(X);
        int2* dst = reinterpret_cast<int2*>(Xb);
        int base = bid * 256 + tid;
#pragma unroll
        for (int i = 0; i < 4; ++i) {
            float4 v = src[base + i * 65536];
            union { __bf16 h[4]; int2 u; } o;
            o.h[0] = (__bf16)v.x; o.h[1] = (__bf16)v.y;
            o.h[2] = (__bf16)v.z; o.h[3] = (__bf16)v.w;
            dst[base + i * 65536] = o.u;
        }
    } else {
        const float* src; __bf16* dst;
        int kt, ft, srcPitch, dstPitch;
        if (bid < 352) {
            int b2 = bid - 256;
            kt = b2 / 24; ft = b2 % 24;
            src = Wqkv; srcPitch = 1536; dst = Wt; dstPitch = 256;
        } else {
            int b2 = bid - 352;
            kt = b2 >> 2; ft = b2 & 3;
            src = Wout; srcPitch = 256;  dst = Wot; dstPitch = 512;
        }
        int k0 = kt * 64, f0 = ft * 64;
#pragma unroll
        for (int rep = 0; rep < 4; ++rep) {
            int idx = rep * 256 + tid;
            int kr = idx >> 4;
            int c4 = idx & 15;
            float4 v = *reinterpret_cast<const float4*>(
                src + (size_t)(k0 + kr) * srcPitch + f0 + c4 * 4);
            *reinterpret_cast<float4*>(&Ws[kr * 68 + c4 * 4]) = v;
        }
        __syncthreads();
        int fr = tid & 63;
        int kg = tid >> 6;
        union { __bf16 h[8]; int4 u; } o0, o1;
#pragma unroll
        for (int j = 0; j < 8; ++j) o0.h[j] = (__bf16)Ws[(kg * 16 + j) * 68 + fr];
#pragma unroll
        for (int j = 0; j < 8; ++j) o1.h[j] = (__bf16)Ws[(kg * 16 + 8 + j) * 68 + fr];
        int4* d = reinterpret_cast<int4*>(dst + (size_t)(f0 + fr) * dstPitch + k0 + kg * 16);
        d[0] = o0.u; d[1] = o1.u;
    }
}

// ============================================================
// Kernel 1: QKV projection, pure bf16. Tile 128x64 (BM x BN), BK=64.
// grid (1536/64, 4096/128) = 768 blocks -> 3 blocks/CU.
// 4 waves in 2x2; wave tile 64x32 (acc 4x2).
// ============================================================
__global__ __launch_bounds__(256) void gemm_qkv_b(
    const __bf16* __restrict__ Xb, const __bf16* __restrict__ Wt,
    __bf16* __restrict__ Q, __bf16* __restrict__ Kb, __bf16* __restrict__ Vt)
{
    __shared__ __bf16 As[128 * 64];   // 16 KB
    __shared__ __bf16 Bs[64 * 64];    // 8 KB
    const int tid  = threadIdx.x;
    const int lane = tid & 63;
    const int wv   = tid >> 6;
    const int wr   = wv >> 1, wc = wv & 1;
    const int m0 = blockIdx.y * 128;
    const int n0 = blockIdx.x * 64;
    const int l15 = lane & 15, l4 = lane >> 4;

    f32x4 zero = {0.f, 0.f, 0.f, 0.f};
    f32x4 acc[4][2];
#pragma unroll
    for (int i = 0; i < 4; ++i)
#pragma unroll
        for (int j = 0; j < 2; ++j) acc[i][j] = zero;

    const int srow8 = lane >> 3;
    const int sslot = lane & 7;

    for (int k0 = 0; k0 < 256; k0 += 64) {
#pragma unroll
        for (int j = 0; j < 4; ++j) {
            int rbase = j * 32 + wv * 8;
            int row   = rbase + srow8;
            int slot  = sslot ^ (row & 7);
            gld_lds16(Xb + (size_t)(m0 + row) * 256 + k0 + slot * 8, &As[rbase * 64]);
        }
#pragma unroll
        for (int j = 0; j < 2; ++j) {
            int rbase = j * 32 + wv * 8;
            int row   = rbase + srow8;
            int slot  = sslot ^ (row & 7);
            gld_lds16(Wt + (size_t)(n0 + row) * 256 + k0 + slot * 8, &Bs[rbase * 64]);
        }
        __syncthreads();

#pragma unroll
        for (int s = 0; s < 2; ++s) {
            bfx8 af[4], bf_[2];
#pragma unroll
            for (int m = 0; m < 4; ++m) {
                int row = wr * 64 + m * 16 + l15;
                af[m] = *reinterpret_cast<const bfx8*>(
                    reinterpret_cast<const char*>(As) + row * 128 +
                    (((s * 4 + l4) * 16) ^ ((row & 7) << 4)));
            }
#pragma unroll
            for (int n = 0; n < 2; ++n) {
                int row = wc * 32 + n * 16 + l15;
                bf_[n] = *reinterpret_cast<const bfx8*>(
                    reinterpret_cast<const char*>(Bs) + row * 128 +
                    (((s * 4 + l4) * 16) ^ ((row & 7) << 4)));
            }
#pragma unroll
            for (int m = 0; m < 4; ++m)
#pragma unroll
                for (int n = 0; n < 2; ++n)
                    acc[m][n] = mfma16(af[m], bf_[n], acc[m][n]);
        }
        __syncthreads();
    }

    const float QSCALE = 0.125f * 1.44269504088896f;
#pragma unroll
    for (int m = 0; m < 4; ++m)
#pragma unroll
        for (int n = 0; n < 2; ++n) {
            int rowb = m0 + wr * 64 + m * 16 + l4 * 4;
            int f    = n0 + wc * 32 + n * 16 + l15;
            if (f < 512) {
#pragma unroll
                for (int r = 0; r < 4; ++r)
                    Q[(size_t)(f >> 6) * (NTOK * DHEAD) + (size_t)(rowb + r) * DHEAD + (f & 63)] =
                        (__bf16)(acc[m][n][r] * QSCALE);
            } else if (f < 1024) {
                int g = f - 512;
#pragma unroll
                for (int r = 0; r < 4; ++r)
                    Kb[(size_t)(g >> 6) * (NTOK * DHEAD) + (size_t)(rowb + r) * DHEAD + (g & 63)] =
                        (__bf16)acc[m][n][r];
            } else {
                int g = f - 1024;
                union { __bf16 h[4]; int2 u; } o;
                o.h[0] = (__bf16)acc[m][n][0]; o.h[1] = (__bf16)acc[m][n][1];
                o.h[2] = (__bf16)acc[m][n][2]; o.h[3] = (__bf16)acc[m][n][3];
                *reinterpret_cast<int2*>(
                    Vt + (size_t)(g >> 6) * (DHEAD * NTOK) + (size_t)(g & 63) * NTOK + rowb) = o.u;
            }
        }
}

// ============================================================
// Kernel 2: flash attention (R13 + deferred l-reduction: one
// cross-half shuffle per kernel instead of per kb-block).
// ============================================================
__global__ __launch_bounds__(512, 4) void attn_fwd(
    const __bf16* __restrict__ Q, const __bf16* __restrict__ Kb,
    const __bf16* __restrict__ Vt,
    unsigned int* __restrict__ Opu, float* __restrict__ Lsum)
{
    const int tid  = threadIdx.x;
    const int lane = tid & 63;
    const int wv   = tid >> 6;          // 0..7
    const int bid = blockIdx.x;
    const int h  = bid & 7;
    const int t2 = bid >> 3;
    const int sp = t2 & (NSPLIT - 1);
    const int qb = t2 >> 2;             // 0..15
    const int l31 = lane & 31;
    const int hi  = lane >> 5;

    const __bf16* Qh = Q  + (size_t)h * NTOK * DHEAD;
    const __bf16* Kh = Kb + (size_t)h * NTOK * DHEAD;
    const __bf16* Vh = Vt + (size_t)h * DHEAD * NTOK;

    __shared__ __bf16 Ks[2][64 * 64];
    __shared__ __bf16 Vs[2][64 * 64];

    const int srow  = tid >> 3;
    const int scol8 = (tid & 7) ^ (srow & 7);

    const int qrow = qb * 256 + wv * 32 + l31;
    bfx8 qf[4];
#pragma unroll
    for (int s = 0; s < 4; ++s)
        qf[s] = *reinterpret_cast<const bfx8*>(
            Qh + (size_t)qrow * DHEAD + s * 16 + hi * 8);

    f32x16 o0, o1;
#pragma unroll
    for (int r = 0; r < 16; ++r) { o0[r] = 0.f; o1[r] = 0.f; }
    float l0 = 0.f;

    const int jbeg = sp * KCHUNK, jend = jbeg + KCHUNK;
    const int ksw = (l31 & 7) << 4;

    auto stage = [&](int bf, int j0) {
        gld_lds16(Kh + (size_t)(j0 + srow) * DHEAD + scol8 * 8, &Ks[bf][wv * 8 * 64]);
        gld_lds16(Vh + (size_t)srow * NTOK + j0 + scol8 * 8,    &Vs[bf][wv * 8 * 64]);
    };

    stage(0, jbeg);
    __syncthreads();

    int buf = 0;
    for (int j0 = jbeg; j0 < jend; j0 += 64) {
        if (j0 + 64 < jend) stage(buf ^ 1, j0 + 64);

        const char* Kt  = reinterpret_cast<const char*>(&Ks[buf][0]);
        const char* Vtc = reinterpret_cast<const char*>(&Vs[buf][0]);

#pragma unroll
        for (int kb = 0; kb < 2; ++kb) {
            // ---- S' = K Q^T : lane holds S[key(r,hi)][q=l31] ----
            const char* Kr = Kt + (kb * 32 + l31) * 128;
            f32x16 sa;
#pragma unroll
            for (int r = 0; r < 16; ++r) sa[r] = 0.f;
            __builtin_amdgcn_s_setprio(1);
#pragma unroll
            for (int s = 0; s < 4; ++s) {
                bfx8 kf = *reinterpret_cast<const bfx8*>(Kr + (((s * 2 + hi) * 16) ^ ksw));
                sa = mfma32(kf, qf[s], sa);
            }
            __builtin_amdgcn_s_setprio(0);

            // ---- P = exp2(S) directly (no max subtraction) ----
            float p0  = __builtin_amdgcn_exp2f(sa[0]);
            float p1  = __builtin_amdgcn_exp2f(sa[1]);
            float p2  = __builtin_amdgcn_exp2f(sa[2]);
            float p3  = __builtin_amdgcn_exp2f(sa[3]);
            float p4  = __builtin_amdgcn_exp2f(sa[4]);
            float p5  = __builtin_amdgcn_exp2f(sa[5]);
            float p6  = __builtin_amdgcn_exp2f(sa[6]);
            float p7  = __builtin_amdgcn_exp2f(sa[7]);
            float p8  = __builtin_amdgcn_exp2f(sa[8]);
            float p9  = __builtin_amdgcn_exp2f(sa[9]);
            float p10 = __builtin_amdgcn_exp2f(sa[10]);
            float p11 = __builtin_amdgcn_exp2f(sa[11]);
            float p12 = __builtin_amdgcn_exp2f(sa[12]);
            float p13 = __builtin_amdgcn_exp2f(sa[13]);
            float p14 = __builtin_amdgcn_exp2f(sa[14]);
            float p15 = __builtin_amdgcn_exp2f(sa[15]);
            l0 += (((p0 + p1) + (p2 + p3)) + ((p4 + p5) + (p6 + p7)))
                + (((p8 + p9) + (p10 + p11)) + ((p12 + p13) + (p14 + p15)));

            unsigned int a0, a1, a2, a3, a4, a5, a6, a7;
            asm("v_cvt_pk_bf16_f32 %0, %1, %2" : "=v"(a0) : "v"(p0),  "v"(p1));
            asm("v_cvt_pk_bf16_f32 %0, %1, %2" : "=v"(a1) : "v"(p2),  "v"(p3));
            asm("v_cvt_pk_bf16_f32 %0, %1, %2" : "=v"(a2) : "v"(p4),  "v"(p5));
            asm("v_cvt_pk_bf16_f32 %0, %1, %2" : "=v"(a3) : "v"(p6),  "v"(p7));
            asm("v_cvt_pk_bf16_f32 %0, %1, %2" : "=v"(a4) : "v"(p8),  "v"(p9));
            asm("v_cvt_pk_bf16_f32 %0, %1, %2" : "=v"(a5) : "v"(p10), "v"(p11));
            asm("v_cvt_pk_bf16_f32 %0, %1, %2" : "=v"(a6) : "v"(p12), "v"(p13));
            asm("v_cvt_pk_bf16_f32 %0, %1, %2" : "=v"(a7) : "v"(p14), "v"(p15));
            asm("v_permlane32_swap_b32 %0, %1" : "+v"(a0), "+v"(a2));
            asm("v_permlane32_swap_b32 %0, %1" : "+v"(a1), "+v"(a3));
            asm("v_permlane32_swap_b32 %0, %1" : "+v"(a4), "+v"(a6));
            asm("v_permlane32_swap_b32 %0, %1" : "+v"(a5), "+v"(a7));
            union { unsigned int u[4]; bfx8 v; } f1, f2;
            f1.u[0] = a0; f1.u[1] = a1; f1.u[2] = a2; f1.u[3] = a3;
            f2.u[0] = a4; f2.u[1] = a5; f2.u[2] = a6; f2.u[3] = a7;

            __builtin_amdgcn_s_setprio(1);
            {
                int cb0 = (kb * 64 + hi * 16) ^ ksw;
                bfx8 vf00 = *reinterpret_cast<const bfx8*>(Vtc + l31 * 128 + cb0);
                o0 = mfma32(f1.v, vf00, o0);
                bfx8 vf01 = *reinterpret_cast<const bfx8*>(Vtc + (32 + l31) * 128 + cb0);
                o1 = mfma32(f1.v, vf01, o1);
                int cb1 = (kb * 64 + 32 + hi * 16) ^ ksw;
                bfx8 vf10 = *reinterpret_cast<const bfx8*>(Vtc + l31 * 128 + cb1);
                o0 = mfma32(f2.v, vf10, o0);
                bfx8 vf11 = *reinterpret_cast<const bfx8*>(Vtc + (32 + l31) * 128 + cb1);
                o1 = mfma32(f2.v, vf11, o1);
            }
            __builtin_amdgcn_s_setprio(0);
        }

        __syncthreads();
        buf ^= 1;
    }

    float l_l = l0 + __shfl_xor(l0, 32, 64);

    // ---- store packed partial O (u32 = 2x bf16) + per-row l ----
#pragma unroll
    for (int r = 0; r < 16; ++r) {
        int q = (r & 3) + 8 * (r >> 2) + 4 * hi;
        size_t row = (size_t)(qb * 256 + wv * 32 + q);
        unsigned int w;
        asm("v_cvt_pk_bf16_f32 %0, %1, %2" : "=v"(w) : "v"(o0[r]), "v"(o1[r]));
        Opu[(((size_t)sp * NTOK + row) * NHEAD + h) * 32 + l31] = w;
    }
    if (hi == 0) {
        Lsum[((size_t)sp * NHEAD + h) * NTOK + qrow] = l_l;
    }
}

// ============================================================
// Kernel 2b: combine NSPLIT packed partials -> O bf16 [4096][512]
// ============================================================
__global__ __launch_bounds__(256) void attn_combine(
    const unsigned int* __restrict__ Opu, const float* __restrict__ Lsum,
    __bf16* __restrict__ O)
{
    int idx = blockIdx.x * 256 + threadIdx.x;      // 4096 * 128
    int row = idx >> 7;
    int c4  = (idx & 127) * 4;
    int h   = c4 >> 6;
    int cl  = c4 & 63;
    int hiSel = cl >> 5;
    int base_cl = cl & 31;

    float denom = 0.f;
    float4 acc = make_float4(0.f, 0.f, 0.f, 0.f);
#pragma unroll
    for (int s = 0; s < NSPLIT; ++s) {
        denom += Lsum[((size_t)s * NHEAD + h) * NTOK + row];
        int4 w = *reinterpret_cast<const int4*>(
            Opu + (((size_t)s * NTOK + row) * NHEAD + h) * 32 + base_cl);
        unsigned int w0 = (unsigned int)w.x, w1 = (unsigned int)w.y;
        unsigned int w2 = (unsigned int)w.z, w3 = (unsigned int)w.w;
        if (hiSel) { w0 >>= 16; w1 >>= 16; w2 >>= 16; w3 >>= 16; }
        union { unsigned int u; float f; } c0, c1, c2, c3;
        c0.u = w0 << 16; c1.u = w1 << 16; c2.u = w2 << 16; c3.u = w3 << 16;
        acc.x += c0.f; acc.y += c1.f; acc.z += c2.f; acc.w += c3.f;
    }
    float inv = 1.f / denom;
    __bf16* op = O + (size_t)row * 512 + c4;
    op[0] = (__bf16)(acc.x * inv); op[1] = (__bf16)(acc.y * inv);
    op[2] = (__bf16)(acc.z * inv); op[3] = (__bf16)(acc.w * inv);
}

// ============================================================
// Kernel 3: output projection, pure bf16 staging.
// ============================================================
__global__ __launch_bounds__(256) void gemm_out_b(
    const __bf16* __restrict__ O, const __bf16* __restrict__ Wot,
    const float* __restrict__ bias, float* __restrict__ out)
{
    __shared__ __bf16 As[64 * 64];
    __shared__ __bf16 Bs[64 * 64];
    const int tid  = threadIdx.x;
    const int lane = tid & 63;
    const int wv   = tid >> 6;
    const int wr   = wv >> 1, wc = wv & 1;
    const int m0 = blockIdx.y * 64;
    const int n0 = blockIdx.x * 64;
    const int l15 = lane & 15, l4 = lane >> 4;

    f32x4 zero = {0.f, 0.f, 0.f, 0.f};
    f32x4 acc[2][2];
#pragma unroll
    for (int i = 0; i < 2; ++i)
#pragma unroll
        for (int j = 0; j < 2; ++j) acc[i][j] = zero;

    const int srow8 = lane >> 3;
    const int sslot = lane & 7;

    for (int k0 = 0; k0 < 512; k0 += 64) {
#pragma unroll
        for (int j = 0; j < 2; ++j) {
            int rbase = j * 32 + wv * 8;
            int row   = rbase + srow8;
            int slot  = sslot ^ (row & 7);
            gld_lds16(O   + (size_t)(m0 + row) * 512 + k0 + slot * 8, &As[rbase * 64]);
            gld_lds16(Wot + (size_t)(n0 + row) * 512 + k0 + slot * 8, &Bs[rbase * 64]);
        }
        __syncthreads();

#pragma unroll
        for (int s = 0; s < 2; ++s) {
            bfx8 af[2], bf_[2];
#pragma unroll
            for (int m = 0; m < 2; ++m) {
                int row = wr * 32 + m * 16 + l15;
                af[m] = *reinterpret_cast<const bfx8*>(
                    reinterpret_cast<const char*>(As) + row * 128 +
                    (((s * 4 + l4) * 16) ^ ((row & 7) << 4)));
            }
#pragma unroll
            for (int n = 0; n < 2; ++n) {
                int row = wc * 32 + n * 16 + l15;
                bf_[n] = *reinterpret_cast<const bfx8*>(
                    reinterpret_cast<const char*>(Bs) + row * 128 +
                    (((s * 4 + l4) * 16) ^ ((row & 7) << 4)));
            }
#pragma unroll
            for (int m = 0; m < 2; ++m)
#pragma unroll
                for (int n = 0; n < 2; ++n)
                    acc[m][n] = mfma16(af[m], bf_[n], acc[m][n]);
        }
        __syncthreads();
    }

#pragma unroll
    for (int m = 0; m < 2; ++m)
#pragma unroll
        for (int n = 0; n < 2; ++n) {
            int col = n0 + wc * 32 + n * 16 + l15;
            float b = bias[col];
#pragma unroll
            for (int r = 0; r < 4; ++r) {
                int row = m0 + wr * 32 + m * 16 + l4 * 4 + r;
                out[(size_t)row * 256 + col] = acc[m][n][r] + b;
            }
        }
}

// ============================================================
extern "C" void kernel_launch(void* const* d_in, const int* in_sizes, int n_in,
                              void* d_out, int out_size, void* d_ws, size_t ws_size,
                              hipStream_t stream) {
    const float* x     = (const float*)d_in[0];
    const float* w_qkv = (const float*)d_in[1];
    const float* w_out = (const float*)d_in[2];
    const float* b_out = (const float*)d_in[3];
    float* out = (float*)d_out;

    __bf16* Q  = (__bf16*)d_ws;
    __bf16* K  = Q  + (size_t)NHEAD * NTOK * DHEAD;
    __bf16* Vt = K  + (size_t)NHEAD * NTOK * DHEAD;
    __bf16* O  = Vt + (size_t)NHEAD * NTOK * DHEAD;
    unsigned int* Opu = (unsigned int*)(O + (size_t)NTOK * 512);
    float* Lsum = (float*)(Opu + (size_t)NSPLIT * NTOK * NHEAD * 32);
    __bf16* Xb = (__bf16*)(Lsum + (size_t)NSPLIT * NHEAD * NTOK);
    __bf16* Wt = Xb + (size_t)NTOK * 256;
    __bf16* Wot = Wt + (size_t)1536 * 256;

    cast_xw     <<<dim3(384), 256, 0, stream>>>(x, w_qkv, w_out, Xb, Wt, Wot);
    gemm_qkv_b  <<<dim3(24, 32), 256, 0, stream>>>(Xb, Wt, Q, K, Vt);
    attn_fwd    <<<dim3((NTOK / 256) * NSPLIT * NHEAD), 512, 0, stream>>>(Q, K, Vt, Opu, Lsum);
    attn_combine<<<dim3(NTOK * 128 / 256), 256, 0, stream>>>(Opu, Lsum, O);
    gemm_out_b  <<<dim3(256 / 64, NTOK / 64), 256, 0, stream>>>(O, Wot, b_out, out);
}